// Round 1
// baseline (655.355 us; speedup 1.0000x reference)
//
#include <hip/hip_runtime.h>
#include <cstdint>
#include <cstddef>

// ---------------- constants ----------------
constexpr int Bn = 4, Cin = 512, Hn = 128, Wn = 128, HWn = Hn * Wn;
constexpr float SCALE = 0.08838834764831845f; // 128^-0.5

typedef unsigned short u16;
typedef unsigned int u32;
using f32x4  = __attribute__((ext_vector_type(4))) float;
using bf16x8 = __attribute__((ext_vector_type(8))) short; // 8 bf16 in 4 VGPRs

#define MFMA(a, b, c) __builtin_amdgcn_mfma_f32_16x16x32_bf16((a), (b), (c), 0, 0, 0)

__device__ __forceinline__ u16 bfu(float f) { // f32 -> bf16 bits, RNE
  u32 u = __float_as_uint(f);
  u += 0x7fffu + ((u >> 16) & 1u);
  return (u16)(u >> 16);
}

// ---------------- workspace layout (bytes) ----------------
constexpr size_t SZ_XT = (size_t)Bn * HWn * 512 * 2;   // x^T bf16 [B][pos][512]
constexpr size_t SZ_QK = (size_t)Bn * 4 * HWn * 128 * 2; // Q/K bf16 [B][h][pos][128]
constexpr size_t SZ_V  = (size_t)Bn * 4 * HWn * 64 * 2;  // V bf16 [B][h][pos][64]
constexpr size_t SZ_O  = (size_t)Bn * 256 * HWn * 4;     // f32
constexpr size_t OFF_XT = 0;
constexpr size_t OFF_Q  = OFF_XT + SZ_XT;
constexpr size_t OFF_K  = OFF_Q + SZ_QK;
constexpr size_t OFF_V  = OFF_K + SZ_QK;
constexpr size_t OFF_OH = OFF_V + SZ_V;   // out_H f32 [B][h][W][64][H]  (i-contiguous)
constexpr size_t OFF_OW = OFF_OH + SZ_O;  // out_W f32 [B][256][H][W]
constexpr size_t OFF_ST = OFF_OW + SZ_O;  // stats f32[512]: mH[128] isH[128] mW[128] isW[128]

// ---------------- K1: x [B,512,HW] f32 -> x^T [B,HW,512] bf16 ----------------
__global__ __launch_bounds__(256) void k_transpose_cast(const float* __restrict__ x,
                                                        u16* __restrict__ xT) {
  __shared__ float tile[32][33];
  const int b = blockIdx.z, c0 = blockIdx.y * 32, p0 = blockIdx.x * 32;
  const int t = threadIdx.x;
  const int pi = t & 31, ci = t >> 5;
  const float* xp = x + ((size_t)b * Cin + c0) * HWn + p0;
  for (int cc = ci; cc < 32; cc += 8) tile[cc][pi] = xp[(size_t)cc * HWn + pi];
  __syncthreads();
  u16* o = xT + ((size_t)b * HWn + p0) * Cin + c0;
  for (int pp = ci; pp < 32; pp += 8) o[(size_t)pp * Cin + pi] = bfu(tile[pi][pp]);
}

// ---------------- K2: grouped QKV projection GEMM (MFMA) ----------------
// D[m=oc(64)][n=pos(128)], K=256 in 2 chunks of 128.  oc tiles: 0..7 Q, 8..15 K, 16..19 V.
__global__ __launch_bounds__(256) void k_proj(
    const u16* __restrict__ xT,
    const float* __restrict__ wq, const float* __restrict__ bq,
    const float* __restrict__ wk, const float* __restrict__ bk,
    const float* __restrict__ wv, const float* __restrict__ bv,
    u16* __restrict__ Q, u16* __restrict__ K, u16* __restrict__ V) {
  __shared__ u16 sm[128 * 128 + 64 * 128]; // xs 32KB + wsm 16KB (wsm reused as out staging)
  u16* xs = sm;
  u16* wsm = sm + 128 * 128;

  const int t = threadIdx.x;
  const int ot = blockIdx.x;      // 0..19
  const int pos0 = blockIdx.y * 128;
  const int b = blockIdx.z;

  const float* wsrc; const float* bsrc; u16* dst; int g, d0, pitch;
  if (ot < 8) {
    int qc0 = ot * 64; g = qc0 >> 8; int n = qc0 >> 7; d0 = qc0 & 127;
    wsrc = wq + (size_t)qc0 * 256; bsrc = bq + qc0;
    dst = Q + (size_t)(b * 4 + n) * HWn * 128; pitch = 128;
  } else if (ot < 16) {
    int kc0 = (ot - 8) * 64; g = kc0 >> 8; int n = kc0 >> 7; d0 = kc0 & 127;
    wsrc = wk + (size_t)kc0 * 256; bsrc = bk + kc0;
    dst = K + (size_t)(b * 4 + n) * HWn * 128; pitch = 128;
  } else {
    int vc0 = (ot - 16) * 64; g = vc0 >> 7; int n = vc0 >> 6; d0 = 0;
    wsrc = wv + (size_t)vc0 * 256; bsrc = bv + vc0;
    dst = V + (size_t)(b * 4 + n) * HWn * 64; pitch = 64;
  }

  const int lane = t & 63, wid = t >> 6, ln = lane & 15, qd = lane >> 4;
  const u16* xrow = xT + ((size_t)b * HWn + pos0) * 512 + g * 256;

  f32x4 acc[8];
#pragma unroll
  for (int i = 0; i < 8; ++i) acc[i] = f32x4{0.f, 0.f, 0.f, 0.f};

  for (int kc = 0; kc < 2; ++kc) {
    __syncthreads();
    // stage W chunk [64 oc][128 cc], f32->bf16, XOR-swizzled per 8-elem block
#pragma unroll
    for (int p = 0; p < 4; ++p) {
      int id = p * 256 + t;
      int oc = id >> 4, kb = id & 15;
      const float* wp = wsrc + (size_t)oc * 256 + kc * 128 + kb * 8;
      u32 pk0 = (u32)bfu(wp[0]) | ((u32)bfu(wp[1]) << 16);
      u32 pk1 = (u32)bfu(wp[2]) | ((u32)bfu(wp[3]) << 16);
      u32 pk2 = (u32)bfu(wp[4]) | ((u32)bfu(wp[5]) << 16);
      u32 pk3 = (u32)bfu(wp[6]) | ((u32)bfu(wp[7]) << 16);
      *(uint4*)&wsm[oc * 128 + (kb ^ (oc & 15)) * 8] = make_uint4(pk0, pk1, pk2, pk3);
    }
    // stage X chunk [128 pos][128 cc] (already bf16 rows in xT)
#pragma unroll
    for (int p = 0; p < 8; ++p) {
      int id = p * 256 + t;
      int pos = id >> 4, kb = id & 15;
      uint4 v = *(const uint4*)(xrow + (size_t)pos * 512 + kc * 128 + kb * 8);
      *(uint4*)&xs[pos * 128 + (kb ^ (pos & 15)) * 8] = v;
    }
    __syncthreads();
    const u16* arow = wsm + (wid * 16 + ln) * 128;
#pragma unroll
    for (int kk = 0; kk < 4; ++kk) {
      int kb = kk * 4 + qd;
      bf16x8 af = *(const bf16x8*)(arow + (kb ^ ln) * 8);
#pragma unroll
      for (int nt = 0; nt < 8; ++nt) {
        int prow = nt * 16 + ln;
        bf16x8 bf_ = *(const bf16x8*)(xs + prow * 128 + (kb ^ ln) * 8);
        acc[nt] = MFMA(af, bf_, acc[nt]);
      }
    }
  }
  __syncthreads();
  // epilogue: +bias, bf16, stage [pos][64 oc] (4-elem swizzle) into wsm alias
  {
    float bias[4];
#pragma unroll
    for (int r = 0; r < 4; ++r) bias[r] = bsrc[wid * 16 + qd * 4 + r];
    int ocb = wid * 4 + qd;
#pragma unroll
    for (int nt = 0; nt < 8; ++nt) {
      int pos = nt * 16 + ln;
      u32 lo = (u32)bfu(acc[nt][0] + bias[0]) | ((u32)bfu(acc[nt][1] + bias[1]) << 16);
      u32 hi = (u32)bfu(acc[nt][2] + bias[2]) | ((u32)bfu(acc[nt][3] + bias[3]) << 16);
      *(uint2*)&wsm[pos * 64 + (ocb ^ (pos & 15)) * 4] = make_uint2(lo, hi);
    }
  }
  __syncthreads();
  // coalesced copy to global: rows of 64 bf16 (128 B) per pos
#pragma unroll
  for (int p = 0; p < 4; ++p) {
    int id = p * 256 + t;
    int pos = id >> 3, off = (id & 7) * 8;
    int ocb0 = off >> 2;
    uint2 g0 = *(const uint2*)&wsm[pos * 64 + ((ocb0) ^ (pos & 15)) * 4];
    uint2 g1 = *(const uint2*)&wsm[pos * 64 + ((ocb0 + 1) ^ (pos & 15)) * 4];
    *(uint4*)(dst + (size_t)(pos0 + pos) * pitch + d0 + off) = make_uint4(g0.x, g0.y, g1.x, g1.y);
  }
}

// ---------------- K3: criss-cross attention, both directions ----------------
// block = (s, b*4+n, dir): 128x128 scores, softmax over keys, PV -> [64 c][128 i]
__global__ __launch_bounds__(256) void k_attn(
    const u16* __restrict__ Qg, const u16* __restrict__ Kg, const u16* __restrict__ Vg,
    float* __restrict__ outH, float* __restrict__ outW) {
  __shared__ u16 sm[64 * 128 + 128 * 128]; // VT 16KB + KP 32KB (KP: K -> P -> Os)
  u16* VT = sm;
  u16* KP = sm + 64 * 128;
  float* Os = (float*)KP;

  const int t = threadIdx.x;
  const int s = blockIdx.x;
  const int b = blockIdx.y >> 2, n = blockIdx.y & 3;
  const int dir = blockIdx.z;                 // 0 = along H, 1 = along W
  const int pos_base = (dir == 0) ? s : s * 128;
  const int step = (dir == 0) ? 128 : 1;

  const u16* qb = Qg + (size_t)(b * 4 + n) * HWn * 128;
  const u16* kb = Kg + (size_t)(b * 4 + n) * HWn * 128;
  const u16* vb = Vg + (size_t)(b * 4 + n) * HWn * 64;

  // stage K rows [j][d], swizzled
#pragma unroll
  for (int p = 0; p < 8; ++p) {
    int id = p * 256 + t;
    int row = id >> 4, kk = id & 15;
    uint4 v = *(const uint4*)(kb + (size_t)(pos_base + row * step) * 128 + kk * 8);
    *(uint4*)&KP[row * 128 + (kk ^ (row & 15)) * 8] = v;
  }
  // stage V transposed: VT[c][j]
#pragma unroll
  for (int p = 0; p < 4; ++p) {
    int id = p * 256 + t;
    int j = id >> 3, cb = id & 7;
    uint4 v = *(const uint4*)(vb + (size_t)(pos_base + j * step) * 64 + cb * 8);
    const u16* pv = (const u16*)&v;
    int jb = j >> 3, jr = j & 7;
#pragma unroll
    for (int e = 0; e < 8; ++e) {
      int c = cb * 8 + e;
      VT[c * 128 + (((jb ^ (c & 15)) << 3) | jr)] = pv[e];
    }
  }
  __syncthreads();

  const int lane = t & 63, wid = t >> 6, ln = lane & 15, qd = lane >> 4;
  f32x4 accS[2][8];
#pragma unroll
  for (int mi = 0; mi < 2; ++mi)
#pragma unroll
    for (int nt = 0; nt < 8; ++nt) accS[mi][nt] = f32x4{0.f, 0.f, 0.f, 0.f};

  // S = Q K^T : A-frags straight from global (each Q element read once)
#pragma unroll
  for (int kk = 0; kk < 4; ++kk) {
    int kbi = kk * 4 + qd;
    bf16x8 a0 = *(const bf16x8*)(qb + (size_t)(pos_base + (wid * 32 + ln) * step) * 128 + kbi * 8);
    bf16x8 a1 = *(const bf16x8*)(qb + (size_t)(pos_base + (wid * 32 + 16 + ln) * step) * 128 + kbi * 8);
#pragma unroll
    for (int nt = 0; nt < 8; ++nt) {
      int row = nt * 16 + ln;
      bf16x8 bf_ = *(const bf16x8*)(KP + row * 128 + (kbi ^ ln) * 8);
      accS[0][nt] = MFMA(a0, bf_, accS[0][nt]);
      accS[1][nt] = MFMA(a1, bf_, accS[1][nt]);
    }
  }
  // softmax over keys: wave owns full rows; reduce in-reg over nt then over quad's 16 lanes
  float rinv[2][4];
#pragma unroll
  for (int mi = 0; mi < 2; ++mi)
#pragma unroll
    for (int r = 0; r < 4; ++r) {
      float mx = accS[mi][0][r];
#pragma unroll
      for (int nt = 1; nt < 8; ++nt) mx = fmaxf(mx, accS[mi][nt][r]);
      mx = fmaxf(mx, __shfl_xor(mx, 1));
      mx = fmaxf(mx, __shfl_xor(mx, 2));
      mx = fmaxf(mx, __shfl_xor(mx, 4));
      mx = fmaxf(mx, __shfl_xor(mx, 8));
      float sum = 0.f;
#pragma unroll
      for (int nt = 0; nt < 8; ++nt) {
        float e = __expf((accS[mi][nt][r] - mx) * SCALE);
        accS[mi][nt][r] = e; sum += e;
      }
      sum += __shfl_xor(sum, 1);
      sum += __shfl_xor(sum, 2);
      sum += __shfl_xor(sum, 4);
      sum += __shfl_xor(sum, 8);
      rinv[mi][r] = 1.f / sum;
    }
  __syncthreads(); // all waves done reading KP as K
  // write P (unnormalized exp) into KP, own rows only (D-layout -> A-layout via LDS)
#pragma unroll
  for (int mi = 0; mi < 2; ++mi) {
    int mbase = (wid * 2 + mi) * 16 + qd * 4;
#pragma unroll
    for (int nt = 0; nt < 8; ++nt) {
      int nb = nt * 2 + (ln >> 3), nr = ln & 7;
#pragma unroll
      for (int r = 0; r < 4; ++r) {
        int m = mbase + r;
        KP[m * 128 + (((nb ^ (m & 15)) << 3) | nr)] = bfu(accS[mi][nt][r]);
      }
    }
  }
  // PV
  f32x4 accO[2][4];
#pragma unroll
  for (int mi = 0; mi < 2; ++mi)
#pragma unroll
    for (int nt = 0; nt < 4; ++nt) accO[mi][nt] = f32x4{0.f, 0.f, 0.f, 0.f};
#pragma unroll
  for (int jj = 0; jj < 4; ++jj) {
    int jb2 = jj * 4 + qd;
    bf16x8 a0 = *(const bf16x8*)(KP + (wid * 32 + ln) * 128 + (jb2 ^ ln) * 8);
    bf16x8 a1 = *(const bf16x8*)(KP + (wid * 32 + 16 + ln) * 128 + (jb2 ^ ln) * 8);
#pragma unroll
    for (int nt = 0; nt < 4; ++nt) {
      int c = nt * 16 + ln;
      bf16x8 bf_ = *(const bf16x8*)(VT + c * 128 + (jb2 ^ (c & 15)) * 8);
      accO[0][nt] = MFMA(a0, bf_, accO[0][nt]);
      accO[1][nt] = MFMA(a1, bf_, accO[1][nt]);
    }
  }
  __syncthreads(); // all waves done reading P / VT
  // stage normalized output [64 c][128 i] f32, 4-elem swizzle (aliases KP)
#pragma unroll
  for (int mi = 0; mi < 2; ++mi) {
    int ib = ((wid * 2 + mi) * 16 + qd * 4) >> 2;
#pragma unroll
    for (int nt = 0; nt < 4; ++nt) {
      int c = nt * 16 + ln;
      f32x4 v;
#pragma unroll
      for (int r = 0; r < 4; ++r) v[r] = accO[mi][nt][r] * rinv[mi][r];
      *(f32x4*)(Os + c * 128 + ((ib ^ (c & 31)) << 2)) = v;
    }
  }
  __syncthreads();
  float* obase; size_t cstride;
  if (dir == 0) { obase = outH + ((size_t)(b * 4 + n) * 128 + s) * 8192; cstride = 128; }
  else          { obase = outW + (size_t)(b * 256 + n * 64) * HWn + (size_t)s * 128; cstride = HWn; }
#pragma unroll
  for (int p = 0; p < 8; ++p) {
    int id = p * 256 + t;
    int c = id >> 5, i4 = id & 31;
    f32x4 v = *(const f32x4*)(Os + c * 128 + ((i4 ^ (c & 31)) << 2));
    *(f32x4*)(obase + (size_t)c * cstride + i4 * 4) = v;
  }
}

// ---------------- K4: BN batch stats (only first 128 channels of each branch) ----------------
__global__ __launch_bounds__(256) void k_bnstats(const float* __restrict__ outH,
                                                 const float* __restrict__ outW,
                                                 float* __restrict__ stats) {
  const int cid = blockIdx.x;        // 0..255
  const int tensor = cid >> 7, ch = cid & 127;
  const int t = threadIdx.x;
  float s1 = 0.f, s2 = 0.f;
  if (tensor == 0) {
    const int n = ch >> 6, c = ch & 63;
    const int i = t & 127;
    for (int o = (t >> 7); o < 512; o += 2) {
      const int b = o >> 7, w = o & 127;
      float v = outH[(size_t)((b * 4 + n) * 128 + w) * 8192 + c * 128 + i];
      s1 += v; s2 += v * v;
    }
  } else {
    for (int f = t; f < 4 * HWn; f += 256) {
      const int b = f >> 14, p2 = f & (HWn - 1);
      float v = outW[(size_t)(b * 256 + ch) * HWn + p2];
      s1 += v; s2 += v * v;
    }
  }
#pragma unroll
  for (int m = 32; m >= 1; m >>= 1) { s1 += __shfl_xor(s1, m); s2 += __shfl_xor(s2, m); }
  __shared__ float r1[4], r2[4];
  if ((t & 63) == 0) { r1[t >> 6] = s1; r2[t >> 6] = s2; }
  __syncthreads();
  if (t == 0) {
    float a1 = r1[0] + r1[1] + r1[2] + r1[3];
    float a2 = r2[0] + r2[1] + r2[2] + r2[3];
    float mean = a1 * (1.f / 65536.f);
    float var = a2 * (1.f / 65536.f) - mean * mean;
    stats[tensor * 256 + ch] = mean;
    stats[tensor * 256 + 128 + ch] = rsqrtf(var + 1e-5f);
  }
}

// ---------------- K5: fused epilogue: out = g*relu(.)+x, p0/p1 = BN ----------------
__global__ __launch_bounds__(256) void k_final(
    const float* __restrict__ x, const float* __restrict__ outH,
    const float* __restrict__ outW, const float* __restrict__ stats,
    const float* __restrict__ bnh_w, const float* __restrict__ bnh_b,
    const float* __restrict__ bnw_w, const float* __restrict__ bnw_b,
    const float* __restrict__ gamma,
    float* __restrict__ out, float* __restrict__ p0, float* __restrict__ p1) {
  __shared__ float lds[32 * 129];
  const int t = threadIdx.x;
  const int w0 = blockIdx.x * 32;
  const int ch = blockIdx.y;
  const int b = blockIdx.z;
  const float gm = gamma[0];
  const float* xp = x + (size_t)(b * 512 + ch) * HWn;
  float* op = out + (size_t)(b * 512 + ch) * HWn;
  if (ch < 256) {
    const int n = ch >> 6, c = ch & 63;
    const float* hb = outH + (size_t)(b * 4 + n) * 128 * 8192 + c * 128;
    for (int ps = 0; ps < 16; ++ps) {
      int wl = ps * 2 + (t >> 7);
      lds[wl * 129 + (t & 127)] = hb[(size_t)(w0 + wl) * 8192 + (t & 127)];
    }
    __syncthreads();
    const bool dop = ch < 128;
    const float mean = dop ? stats[ch] : 0.f;
    const float istd = dop ? stats[128 + ch] : 0.f;
    const float bw = dop ? bnh_w[ch] : 0.f;
    const float bb = dop ? bnh_b[ch] : 0.f;
    float* pp = p0 + (size_t)(b * 128 + ch) * HWn;
    const int w = t & 31, h0 = t >> 5;
    for (int hh = 0; hh < 16; ++hh) {
      int h = hh * 8 + h0;
      float v = lds[w * 129 + h];
      int gi = h * 128 + w0 + w;
      op[gi] = gm * fmaxf(v, 0.f) + xp[gi];
      if (dop) pp[gi] = (v - mean) * istd * bw + bb;
    }
  } else {
    const int cw = ch - 256;
    const float* wbp = outW + (size_t)(b * 256 + cw) * HWn;
    const bool dop = cw < 128;
    const float mean = dop ? stats[256 + cw] : 0.f;
    const float istd = dop ? stats[384 + cw] : 0.f;
    const float bw = dop ? bnw_w[cw] : 0.f;
    const float bb = dop ? bnw_b[cw] : 0.f;
    float* pp = p1 + (size_t)(b * 128 + cw) * HWn;
    for (int it = 0; it < 16; ++it) {
      int fl = it * 256 + t;
      int h = fl >> 5, w = fl & 31;
      int gi = h * 128 + w0 + w;
      float v = wbp[gi];
      op[gi] = gm * fmaxf(v, 0.f) + xp[gi];
      if (dop) pp[gi] = (v - mean) * istd * bw + bb;
    }
  }
}

// ---------------- launch ----------------
extern "C" void kernel_launch(void* const* d_in, const int* in_sizes, int n_in,
                              void* d_out, int out_size, void* d_ws, size_t ws_size,
                              hipStream_t stream) {
  (void)in_sizes; (void)n_in; (void)out_size; (void)ws_size;
  const float* x    = (const float*)d_in[0];
  const float* wq   = (const float*)d_in[1];
  const float* bq   = (const float*)d_in[2];
  const float* wk   = (const float*)d_in[3];
  const float* bk   = (const float*)d_in[4];
  const float* wv   = (const float*)d_in[5];
  const float* bv   = (const float*)d_in[6];
  const float* bnhw = (const float*)d_in[7];
  const float* bnhb = (const float*)d_in[8];
  const float* bnww = (const float*)d_in[9];
  const float* bnwb = (const float*)d_in[10];
  const float* gamma = (const float*)d_in[11];

  char* ws = (char*)d_ws;
  u16* xT = (u16*)(ws + OFF_XT);
  u16* Q  = (u16*)(ws + OFF_Q);
  u16* K  = (u16*)(ws + OFF_K);
  u16* V  = (u16*)(ws + OFF_V);
  float* oH = (float*)(ws + OFF_OH);
  float* oW = (float*)(ws + OFF_OW);
  float* st = (float*)(ws + OFF_ST);

  float* out = (float*)d_out;
  float* p0 = out + (size_t)Bn * 512 * HWn;
  float* p1 = p0 + (size_t)Bn * 128 * HWn;

  k_transpose_cast<<<dim3(512, 16, 4), 256, 0, stream>>>(x, xT);
  k_proj<<<dim3(20, 128, 4), 256, 0, stream>>>(xT, wq, bq, wk, bk, wv, bv, Q, K, V);
  k_attn<<<dim3(128, 16, 2), 256, 0, stream>>>(Q, K, V, oH, oW);
  k_bnstats<<<dim3(256), 256, 0, stream>>>(oH, oW, st);
  k_final<<<dim3(4, 512, 4), 256, 0, stream>>>(x, oH, oW, st, bnhw, bnhb, bnww, bnwb, gamma,
                                               out, p0, p1);
}